// Round 4
// baseline (305.124 us; speedup 1.0000x reference)
//
#include <hip/hip_runtime.h>

// RelationGAT, algebraically collapsed:
//   A  = Wq^T @ Wk            (A[j][d]  = sum_o Wq[o][j]*Wk[o][d])
//   M  = Wv @ Wk,  MT = M^T   (MT[d][t] = sum_o Wv[t][o]*Wk[o][d])
//   P  = X @ A                                  [B,128]
//   scores[b,n] = P[b,:] . nbr[b,n,:];  attn = softmax_n
//   NBAR[b,:]   = sum_n attn[b,n]*nbr[b,n,:]
//   OUT = NBAR @ MT  (out[b,t] = sum_d NBAR[b,d]*MT[d][t])
//
// ROUND 4 = ATTRIBUTION EXPERIMENT: attn_rows launched 3x (idempotent).
// T_attn = (dur_us - 148.2) / 2.  Everything else identical to round 3.

#define NB 16384
#define NNBR 50
#define DIM 128

// ---------------- cross-lane add helpers -------------------------------------
template <int CTRL>
__device__ __forceinline__ float dpp_add(float x) {
  int v = __builtin_amdgcn_update_dpp(0, __builtin_bit_cast(int, x), CTRL,
                                      0xF, 0xF, true);
  return x + __builtin_bit_cast(float, v);
}

// sum over each 32-lane half (all lanes of the half get the result)
__device__ __forceinline__ float half_sum(float x) {
  x = dpp_add<0xB1>(x);   // quad_perm {1,0,3,2}  : xor 1
  x = dpp_add<0x4E>(x);   // quad_perm {2,3,0,1}  : xor 2
  x = dpp_add<0x141>(x);  // row_half_mirror      : folds 4-groups within 8
  x = dpp_add<0x140>(x);  // row_mirror           : folds 8-groups within 16
  x += __shfl_xor(x, 16, 64);                    // folds 16-groups within 32
  return x;
}

// ---------------- K1: A and MT, LDS-staged (latency-tolerant) ----------------
__global__ __launch_bounds__(256) void precompute_weights(
    const float* __restrict__ Wq, const float* __restrict__ Wk,
    const float* __restrict__ Wv, float* __restrict__ A,
    float* __restrict__ MT) {
  __shared__ float wk[128 * 128];   // 64 KB
  __shared__ float wrow[8 * 128];   // 4 KB
  int t = threadIdx.x;
  int g = blockIdx.x;
  bool isA = g < 16;
  int r0 = (g & 15) * 8;

  const float4* wk4 = (const float4*)Wk;
  float4* wkl4 = (float4*)wk;
  #pragma unroll
  for (int i = 0; i < 16; ++i) wkl4[t + i * 256] = wk4[t + i * 256];

  if (isA) {
    #pragma unroll
    for (int i = 0; i < 4; ++i) {            // wrow[q][o] = Wq[o][r0+q]
      int idx = t + i * 256;                 // 0..1023
      int q = idx >> 7, o = idx & 127;
      wrow[q * 128 + o] = Wq[o * 128 + r0 + q];
    }
  } else {
    const float4* wv4 = (const float4*)(Wv + r0 * 128);
    float4* wr4 = (float4*)wrow;             // wrow[q][o] = Wv[r0+q][o]
    if (t < 256) wr4[t] = wv4[t];
  }
  __syncthreads();

  int d = t & 127;
  int h = (t >> 7) * 4;
  float acc[4] = {0.f, 0.f, 0.f, 0.f};
  #pragma unroll 8
  for (int o = 0; o < 128; ++o) {
    float b = wk[o * 128 + d];
    #pragma unroll
    for (int qq = 0; qq < 4; ++qq)
      acc[qq] += wrow[(h + qq) * 128 + o] * b;
  }
  if (isA) {
    #pragma unroll
    for (int qq = 0; qq < 4; ++qq) A[(r0 + h + qq) * 128 + d] = acc[qq];
  } else {
    #pragma unroll
    for (int qq = 0; qq < 4; ++qq) MT[d * 128 + r0 + h + qq] = acc[qq];
  }
}

// ---------------- K2/K4: C[b,c] = sum_j L[b,j] * R[j*128+c]  (M=16384,K=N=128)
__global__ __launch_bounds__(256) void gemm128(const float* __restrict__ L,
                                               const float* __restrict__ R,
                                               float* __restrict__ C) {
  int t = threadIdx.x;
  int cg = t & 31;
  int s = t >> 5;
  int c0 = cg * 4;
  int b0 = blockIdx.x * 32 + s * 4;

  float4 acc[4];
  #pragma unroll
  for (int i = 0; i < 4; ++i) acc[i] = make_float4(0.f, 0.f, 0.f, 0.f);

  for (int j = 0; j < 128; j += 4) {
    float4 r0 = *(const float4*)(R + (j + 0) * 128 + c0);
    float4 r1 = *(const float4*)(R + (j + 1) * 128 + c0);
    float4 r2 = *(const float4*)(R + (j + 2) * 128 + c0);
    float4 r3 = *(const float4*)(R + (j + 3) * 128 + c0);
    #pragma unroll
    for (int i = 0; i < 4; ++i) {
      float4 lv = *(const float4*)(L + (size_t)(b0 + i) * 128 + j);
      acc[i].x += lv.x * r0.x + lv.y * r1.x + lv.z * r2.x + lv.w * r3.x;
      acc[i].y += lv.x * r0.y + lv.y * r1.y + lv.z * r2.y + lv.w * r3.y;
      acc[i].z += lv.x * r0.z + lv.y * r1.z + lv.z * r2.z + lv.w * r3.z;
      acc[i].w += lv.x * r0.w + lv.y * r1.w + lv.z * r2.w + lv.w * r3.w;
    }
  }
  #pragma unroll
  for (int i = 0; i < 4; ++i)
    *(float4*)(C + (size_t)(b0 + i) * 128 + c0) = acc[i];
}

// ---------------- K3: stream neighbor once; online softmax + weighted sum ----
__global__ __launch_bounds__(256) void attn_rows(const float* __restrict__ P,
                                                 const float* __restrict__ nbr,
                                                 float* __restrict__ NBAR) {
  int wave = threadIdx.x >> 6;
  int lane = threadIdx.x & 63;
  int b = blockIdx.x * 4 + wave;

  float4 p = ((const float4*)(P + (size_t)b * DIM))[lane & 31];
  const float4* nrow = (const float4*)(nbr + (size_t)b * NNBR * DIM);

  float m = -INFINITY, l = 0.f;
  float4 acc = make_float4(0.f, 0.f, 0.f, 0.f);

  float4 v = nrow[lane];  // pair 0 (neighbors 0,1)
  #pragma unroll 5
  for (int np = 0; np < 25; ++np) {
    int nxt = (np + 1 < 25) ? (np + 1) : np;
    float4 vn = nrow[nxt * 64 + lane];

    float partial = p.x * v.x + p.y * v.y + p.z * v.z + p.w * v.w;
    float s = half_sum(partial);
    float so = __shfl_xor(s, 32, 64);
    float mn = fmaxf(m, fmaxf(s, so));
    float scale = __expf(m - mn);
    float e = __expf(s - mn);
    l = l * scale + e;
    acc.x = acc.x * scale + e * v.x;
    acc.y = acc.y * scale + e * v.y;
    acc.z = acc.z * scale + e * v.z;
    acc.w = acc.w * scale + e * v.w;
    m = mn;
    v = vn;
  }

  l += __shfl_xor(l, 32, 64);
  acc.x += __shfl_xor(acc.x, 32, 64);
  acc.y += __shfl_xor(acc.y, 32, 64);
  acc.z += __shfl_xor(acc.z, 32, 64);
  acc.w += __shfl_xor(acc.w, 32, 64);

  if (lane < 32) {
    float inv = 1.f / l;
    float4 o = make_float4(acc.x * inv, acc.y * inv, acc.z * inv, acc.w * inv);
    ((float4*)(NBAR + (size_t)b * DIM))[lane] = o;
  }
}

// ---------------- launcher ---------------------------------------------------
extern "C" void kernel_launch(void* const* d_in, const int* in_sizes, int n_in,
                              void* d_out, int out_size, void* d_ws,
                              size_t ws_size, hipStream_t stream) {
  const float* x   = (const float*)d_in[0];
  const float* nbr = (const float*)d_in[1];
  const float* Wq  = (const float*)d_in[2];
  const float* Wk  = (const float*)d_in[3];
  const float* Wv  = (const float*)d_in[4];
  float* out = (float*)d_out;

  char* ws = (char*)d_ws;
  float* A    = (float*)(ws);                          // 64 KB
  float* MT   = (float*)(ws + 65536);                  // 64 KB
  float* P    = (float*)(ws + 131072);                 // 8 MB
  float* NBAR = (float*)(ws + 131072 + 8388608);       // 8 MB

  precompute_weights<<<32, 256, 0, stream>>>(Wq, Wk, Wv, A, MT);
  gemm128<<<NB / 32, 256, 0, stream>>>(x, A, P);       // P = X @ A
  // --- attribution: 3x idempotent attn launches; T_attn=(dur-148.2)/2 ---
  attn_rows<<<NB / 4, 256, 0, stream>>>(P, nbr, NBAR);
  attn_rows<<<NB / 4, 256, 0, stream>>>(P, nbr, NBAR);
  attn_rows<<<NB / 4, 256, 0, stream>>>(P, nbr, NBAR);
  gemm128<<<NB / 32, 256, 0, stream>>>(NBAR, MT, out); // OUT = NBAR @ MT
}

// Round 5
// 117.473 us; speedup vs baseline: 2.5974x; 2.5974x over previous
//
#include <hip/hip_runtime.h>

// RelationGAT, algebraically collapsed AND fully fused:
//   K1: A = Wq^T@Wk (A[j][d]), MT[d][t] = (Wv@Wk)[t][d]
//   K2 (one pass over neighbor, per wave = 4 batch rows):
//       p_b   = x_b @ A                        (on the fly, A via L1)
//       s_n   = p_b . nbr[b,n,:]; online softmax; nbar_b = sum attn_n nbr
//       out_b = nbar_b @ MT                    (MT via L1, nbar via LDS)

#define NB 16384
#define NNBR 50
#define DIM 128
#define ROWS_W 4  // batch rows per wave

// ---------------- cross-lane add helpers -------------------------------------
template <int CTRL>
__device__ __forceinline__ float dpp_add(float x) {
  int v = __builtin_amdgcn_update_dpp(0, __builtin_bit_cast(int, x), CTRL,
                                      0xF, 0xF, true);
  return x + __builtin_bit_cast(float, v);
}

// sum over each 32-lane half (all lanes of the half get the result)
__device__ __forceinline__ float half_sum(float x) {
  x = dpp_add<0xB1>(x);   // xor 1
  x = dpp_add<0x4E>(x);   // xor 2
  x = dpp_add<0x141>(x);  // row_half_mirror
  x = dpp_add<0x140>(x);  // row_mirror
  x += __shfl_xor(x, 16, 64);
  return x;
}

// ---------------- K1: A and MT, LDS-staged (unchanged from R3) ---------------
__global__ __launch_bounds__(256) void precompute_weights(
    const float* __restrict__ Wq, const float* __restrict__ Wk,
    const float* __restrict__ Wv, float* __restrict__ A,
    float* __restrict__ MT) {
  __shared__ float wk[128 * 128];   // 64 KB
  __shared__ float wrow[8 * 128];   // 4 KB
  int t = threadIdx.x;
  int g = blockIdx.x;
  bool isA = g < 16;
  int r0 = (g & 15) * 8;

  const float4* wk4 = (const float4*)Wk;
  float4* wkl4 = (float4*)wk;
  #pragma unroll
  for (int i = 0; i < 16; ++i) wkl4[t + i * 256] = wk4[t + i * 256];

  if (isA) {
    #pragma unroll
    for (int i = 0; i < 4; ++i) {            // wrow[q][o] = Wq[o][r0+q]
      int idx = t + i * 256;
      int q = idx >> 7, o = idx & 127;
      wrow[q * 128 + o] = Wq[o * 128 + r0 + q];
    }
  } else {
    const float4* wv4 = (const float4*)(Wv + r0 * 128);
    float4* wr4 = (float4*)wrow;             // wrow[q][o] = Wv[r0+q][o]
    if (t < 256) wr4[t] = wv4[t];
  }
  __syncthreads();

  int d = t & 127;
  int h = (t >> 7) * 4;
  float acc[4] = {0.f, 0.f, 0.f, 0.f};
  #pragma unroll 8
  for (int o = 0; o < 128; ++o) {
    float b = wk[o * 128 + d];
    #pragma unroll
    for (int qq = 0; qq < 4; ++qq)
      acc[qq] += wrow[(h + qq) * 128 + o] * b;
  }
  if (isA) {
    #pragma unroll
    for (int qq = 0; qq < 4; ++qq) A[(r0 + h + qq) * 128 + d] = acc[qq];
  } else {
    #pragma unroll
    for (int qq = 0; qq < 4; ++qq) MT[d * 128 + r0 + h + qq] = acc[qq];
  }
}

// ---------------- K2: fused P + attention + output projection ----------------
// 4 waves/block, 4 rows/wave -> 16 rows/block, grid = 1024.
__global__ __launch_bounds__(256) void fused_attn(
    const float* __restrict__ x, const float* __restrict__ A,
    const float* __restrict__ MT, const float* __restrict__ nbr,
    float* __restrict__ out) {
  __shared__ float nbar_s[4][ROWS_W][128];  // 8 KB
  int wave = threadIdx.x >> 6;
  int lane = threadIdx.x & 63;
  int b0 = (blockIdx.x * 4 + wave) * ROWS_W;
  int c0 = (lane & 31) * 4;

  // ---- phase 1: p4[r] = P[b0+r][c0..c0+3]  (replicated across wave halves)
  float4 p4[ROWS_W] = {};
  for (int j = 0; j < 128; j += 4) {
    float4 xv[ROWS_W];
    #pragma unroll
    for (int r = 0; r < ROWS_W; ++r)
      xv[r] = *(const float4*)(x + (size_t)(b0 + r) * DIM + j);  // bcast via L1
    #pragma unroll
    for (int jj = 0; jj < 4; ++jj) {
      float4 a = *(const float4*)(A + (j + jj) * 128 + c0);      // 512B coalesced
      #pragma unroll
      for (int r = 0; r < ROWS_W; ++r) {
        float xs = (jj == 0) ? xv[r].x : (jj == 1) ? xv[r].y
                 : (jj == 2) ? xv[r].z : xv[r].w;
        p4[r].x += xs * a.x;
        p4[r].y += xs * a.y;
        p4[r].z += xs * a.z;
        p4[r].w += xs * a.w;
      }
    }
  }

  // ---- phase 2: stream neighbors, online softmax (pair trick per row)
  const float4* nr0 = (const float4*)(nbr + (size_t)b0 * NNBR * DIM);
  float m[ROWS_W], l[ROWS_W];
  float4 acc[ROWS_W], v[ROWS_W], vn[ROWS_W];
  #pragma unroll
  for (int r = 0; r < ROWS_W; ++r) {
    m[r] = -INFINITY;
    l[r] = 0.f;
    acc[r] = make_float4(0.f, 0.f, 0.f, 0.f);
    v[r] = nr0[(size_t)r * (NNBR * 32) + lane];  // pair 0 of row r
  }

  for (int np = 0; np < 25; ++np) {
    int nxt = (np + 1 < 25) ? (np + 1) : np;
    #pragma unroll
    for (int r = 0; r < ROWS_W; ++r)
      vn[r] = nr0[(size_t)r * (NNBR * 32) + nxt * 64 + lane];

    #pragma unroll
    for (int r = 0; r < ROWS_W; ++r) {
      float partial = p4[r].x * v[r].x + p4[r].y * v[r].y +
                      p4[r].z * v[r].z + p4[r].w * v[r].w;
      float s = half_sum(partial);
      float so = __shfl_xor(s, 32, 64);
      float mn = fmaxf(m[r], fmaxf(s, so));
      float scale = __expf(m[r] - mn);
      float e = __expf(s - mn);
      l[r] = l[r] * scale + e;
      acc[r].x = acc[r].x * scale + e * v[r].x;
      acc[r].y = acc[r].y * scale + e * v[r].y;
      acc[r].z = acc[r].z * scale + e * v[r].z;
      acc[r].w = acc[r].w * scale + e * v[r].w;
      m[r] = mn;
      v[r] = vn[r];
    }
  }

  // merge half-wave accumulators; stash normalized nbar in LDS
  #pragma unroll
  for (int r = 0; r < ROWS_W; ++r) {
    l[r] += __shfl_xor(l[r], 32, 64);
    acc[r].x += __shfl_xor(acc[r].x, 32, 64);
    acc[r].y += __shfl_xor(acc[r].y, 32, 64);
    acc[r].z += __shfl_xor(acc[r].z, 32, 64);
    acc[r].w += __shfl_xor(acc[r].w, 32, 64);
  }
  if (lane < 32) {
    #pragma unroll
    for (int r = 0; r < ROWS_W; ++r) {
      float inv = 1.f / l[r];
      float4 o4 = make_float4(acc[r].x * inv, acc[r].y * inv,
                              acc[r].z * inv, acc[r].w * inv);
      *(float4*)&nbar_s[wave][r][c0] = o4;
    }
  }
  __syncthreads();

  // ---- phase 3: out[b][t] = sum_d nbar[d] * MT[d][t]; lane covers t=2*lane
  float2 o[ROWS_W];
  #pragma unroll
  for (int r = 0; r < ROWS_W; ++r) o[r] = make_float2(0.f, 0.f);

  for (int d = 0; d < 128; d += 4) {
    float4 nb[ROWS_W];
    #pragma unroll
    for (int r = 0; r < ROWS_W; ++r)
      nb[r] = *(const float4*)&nbar_s[wave][r][d];  // ds_read_b128 broadcast
    #pragma unroll
    for (int dd = 0; dd < 4; ++dd) {
      float2 mt = ((const float2*)(MT + (d + dd) * 128))[lane];  // 512B coalesced
      #pragma unroll
      for (int r = 0; r < ROWS_W; ++r) {
        float nv = (dd == 0) ? nb[r].x : (dd == 1) ? nb[r].y
                 : (dd == 2) ? nb[r].z : nb[r].w;
        o[r].x += nv * mt.x;
        o[r].y += nv * mt.y;
      }
    }
  }
  #pragma unroll
  for (int r = 0; r < ROWS_W; ++r)
    ((float2*)(out + (size_t)(b0 + r) * DIM))[lane] = o[r];
}

// ---------------- launcher ---------------------------------------------------
extern "C" void kernel_launch(void* const* d_in, const int* in_sizes, int n_in,
                              void* d_out, int out_size, void* d_ws,
                              size_t ws_size, hipStream_t stream) {
  const float* x   = (const float*)d_in[0];
  const float* nbr = (const float*)d_in[1];
  const float* Wq  = (const float*)d_in[2];
  const float* Wk  = (const float*)d_in[3];
  const float* Wv  = (const float*)d_in[4];
  float* out = (float*)d_out;

  char* ws = (char*)d_ws;
  float* A  = (float*)(ws);            // 64 KB
  float* MT = (float*)(ws + 65536);    // 64 KB

  precompute_weights<<<32, 256, 0, stream>>>(Wq, Wk, Wv, A, MT);
  fused_attn<<<NB / (4 * ROWS_W), 256, 0, stream>>>(x, A, MT, nbr, out);
}